// Round 6
// baseline (257.727 us; speedup 1.0000x reference)
//
#include <hip/hip_runtime.h>
#include <hip/hip_cooperative_groups.h>
#include <type_traits>

namespace cg = cooperative_groups;

#define N_NODES 100000
#define N_EDGES 640000
#define HIDDEN 128

// One cooperative kernel: grid == buckets.
#define NBKT 250              // buckets
#define NB   400              // nodes per bucket; NBKT*NB == N_NODES
#define GTHR 512              // threads per block
#define EPT  5                // edges/thread: NBKT*GTHR*EPT == N_EDGES
#define BLK_RECS (GTHR * EPT) // 2560 records partitioned per block

// ---------------------------------------------------------------------------
// Single cooperative kernel.
//   phase 0: zero cursors (1 slot/block), block 0 packs weights
//   phase A: LDS-sort partition of edges into per-bucket global regions
//   phase B: bucket-local LDS aggregation + fused MLP (weights via wave-
//            uniform packed loads -> scalar path); records kept in LDS
//   phase C: layer-2 scalar aggregation from LDS records, single out store
// Registers (sroot) and LDS (srec) persist across grid.sync().
// ---------------------------------------------------------------------------
template <int CAPW>
__global__ __launch_bounds__(GTHR, 2) void mega_kernel(
    const int* __restrict__ ei, const float* __restrict__ ea,
    const float* __restrict__ x,
    const float* __restrict__ W1_rel, const float* __restrict__ b1,
    const float* __restrict__ W1_root, const float* __restrict__ W2_rel,
    const float* __restrict__ b2, const float* __restrict__ W2_root,
    float* __restrict__ packed, int* __restrict__ cursor,
    uint2* __restrict__ recs, float* __restrict__ s_rel,
    float* __restrict__ out) {
    cg::grid_group grid = cg::this_grid();

    __shared__ uint2 srec[CAPW];          // phase A: sorted block recs; B/C: bucket recs
    __shared__ int   hist[NBKT];
    __shared__ int   start[NBKT + 1];
    __shared__ int   wcur[NBKT];
    __shared__ int   gbase[NBKT];
    __shared__ float accf[NB * 4];        // phase B: agg1; phase C: first NB reused

    const int tid = threadIdx.x;
    const int bid = blockIdx.x;

    // ---------------- phase 0 ----------------
    if (tid == 0) cursor[bid] = 0;
    if (bid == 0 && tid < HIDDEN) {
        float* p = packed + tid * 12;
#pragma unroll
        for (int k = 0; k < 4; ++k) p[k]     = W1_rel[k * HIDDEN + tid];
#pragma unroll
        for (int k = 0; k < 4; ++k) p[4 + k] = W1_root[k * HIDDEN + tid];
        p[8]  = b1[tid];
        p[9]  = W2_rel[tid];
        p[10] = W2_root[tid];
        p[11] = 0.f;
    }
    __threadfence();
    grid.sync();

    // ---------------- phase A: partition ----------------
    for (int i = tid; i < NBKT; i += GTHR) hist[i] = 0;
    __syncthreads();

    int   dsts[EPT];
    int   srcs[EPT];
    float wts[EPT];
    const int e0 = bid * BLK_RECS + tid;
#pragma unroll
    for (int k = 0; k < EPT; ++k) {
        int e = e0 + k * GTHR;
        srcs[k] = ei[e];
        dsts[k] = ei[N_EDGES + e];
        wts[k]  = ea[e];
        atomicAdd(&hist[dsts[k] / NB], 1);
    }
    __syncthreads();

    // Single-wave exclusive scan of hist -> start/wcur.
    if (tid < 64) {
        int base = 0;
        for (int c = 0; c < NBKT; c += 64) {
            int idx = c + tid;
            int v = (idx < NBKT) ? hist[idx] : 0;
            int orig = v;
#pragma unroll
            for (int off = 1; off < 64; off <<= 1) {
                int t = __shfl_up(v, off);
                if (tid >= off) v += t;
            }
            if (idx < NBKT) {
                start[idx] = base + v - orig;
                wcur[idx]  = base + v - orig;
            }
            base += __shfl(v, 63);
        }
        if (tid == 0) start[NBKT] = BLK_RECS;
    }
    __syncthreads();

    // Reserve global bucket space.
    for (int i = tid; i < NBKT; i += GTHR) {
        int h = hist[i];
        gbase[i] = h ? atomicAdd(&cursor[i], h) : 0;
    }
    __syncthreads();

    // Scatter records into LDS in bucket-sorted order.
#pragma unroll
    for (int k = 0; k < EPT; ++k) {
        int d  = dsts[k];
        int b  = d / NB;
        int dl = d - b * NB;
        int slot = atomicAdd(&wcur[b], 1);
        srec[slot] = make_uint2((unsigned)srcs[k] | ((unsigned)dl << 17),
                                __float_as_uint(wts[k]));
    }
    __syncthreads();

    // Stream sorted runs to global; bucket via binary search on start[].
    for (int j = tid; j < BLK_RECS; j += GTHR) {
        int lo = 0, hi = NBKT;
        while (hi - lo > 1) {
            int mid = (lo + hi) >> 1;
            if (start[mid] <= j) lo = mid; else hi = mid;
        }
        int off = gbase[lo] + (j - start[lo]);
        if (off < CAPW)
            recs[(size_t)lo * CAPW + off] = srec[j];
    }
    __threadfence();
    grid.sync();

    // ---------------- phase B: agg1 + fused MLP (bucket bid) ----------------
    for (int i = tid; i < NB * 4; i += GTHR) accf[i] = 0.f;
    __syncthreads();

    const int cnt = min(cursor[bid], CAPW);
    const uint2* rg = recs + (size_t)bid * CAPW;
    for (int i = tid; i < cnt; i += GTHR) {
        uint2 rec = rg[i];
        srec[i] = rec;                      // keep for phase C
        int src = rec.x & 0x1FFFF;
        int dl  = rec.x >> 17;
        float w = __uint_as_float(rec.y);
        float4 xv = reinterpret_cast<const float4*>(x)[src];
        atomicAdd(&accf[dl * 4 + 0], xv.x * w);
        atomicAdd(&accf[dl * 4 + 1], xv.y * w);
        atomicAdd(&accf[dl * 4 + 2], xv.z * w);
        atomicAdd(&accf[dl * 4 + 3], xv.w * w);
    }
    __syncthreads();

    float sroot = 0.f;                      // persists into phase C
    const float b2v = b2[0];
    if (tid < NB) {
        const int n = bid * NB + tid;
        float4 xv = reinterpret_cast<const float4*>(x)[n];
        float4 av = make_float4(accf[tid * 4 + 0], accf[tid * 4 + 1],
                                accf[tid * 4 + 2], accf[tid * 4 + 3]);
        const float4* pw = reinterpret_cast<const float4*>(packed);
        float srel = 0.f;
#pragma unroll 4
        for (int j = 0; j < HIDDEN; ++j) {
            float4 wr = pw[j * 3 + 0];      // W1_rel[0..3][j]
            float4 wo = pw[j * 3 + 1];      // W1_root[0..3][j]
            float4 wb = pw[j * 3 + 2];      // b1, W2_rel, W2_root, pad
            float pre = wb.x
                      + av.x * wr.x + av.y * wr.y + av.z * wr.z + av.w * wr.w
                      + xv.x * wo.x + xv.y * wo.y + xv.z * wo.z + xv.w * wo.w;
            float h = fmaxf(pre, 0.f);
            srel  += h * wb.y;
            sroot += h * wb.z;
        }
        s_rel[n] = srel;
    }
    __threadfence();
    grid.sync();

    // ---------------- phase C: layer-2 aggregation from LDS records --------
    for (int i = tid; i < NB; i += GTHR) accf[i] = 0.f;
    __syncthreads();

    for (int i = tid; i < cnt; i += GTHR) {
        uint2 rec = srec[i];
        int src = rec.x & 0x1FFFF;
        int dl  = rec.x >> 17;
        atomicAdd(&accf[dl], s_rel[src] * __uint_as_float(rec.y));
    }
    __syncthreads();

    if (tid < NB)
        out[bid * NB + tid] = sroot + b2v + accf[tid];
}

// ---------------------------------------------------------------------------
// Legacy fallback (ws too small): direct global-atomic path.
// ---------------------------------------------------------------------------
__global__ void prep_legacy(int* __restrict__ unused,
                            const float* __restrict__ W1_rel,
                            const float* __restrict__ b1,
                            const float* __restrict__ W1_root,
                            const float* __restrict__ W2_rel,
                            const float* __restrict__ W2_root,
                            float* __restrict__ packed) {
    int t = threadIdx.x;
    if (t < HIDDEN) {
        float* p = packed + t * 12;
#pragma unroll
        for (int k = 0; k < 4; ++k) p[k]     = W1_rel[k * HIDDEN + t];
#pragma unroll
        for (int k = 0; k < 4; ++k) p[4 + k] = W1_root[k * HIDDEN + t];
        p[8]  = b1[t];
        p[9]  = W2_rel[t];
        p[10] = W2_root[t];
        p[11] = 0.f;
    }
}

__global__ void scatter1_legacy(const int* __restrict__ ei, const float* __restrict__ ea,
                                const float* __restrict__ x, float* __restrict__ agg) {
    int e = blockIdx.x * blockDim.x + threadIdx.x;
    if (e >= N_EDGES) return;
    int src = ei[e], dst = ei[N_EDGES + e];
    float w = ea[e];
    float4 xv = reinterpret_cast<const float4*>(x)[src];
    atomicAdd(&agg[dst * 4 + 0], xv.x * w);
    atomicAdd(&agg[dst * 4 + 1], xv.y * w);
    atomicAdd(&agg[dst * 4 + 2], xv.z * w);
    atomicAdd(&agg[dst * 4 + 3], xv.w * w);
}

__global__ __launch_bounds__(256) void node_legacy(const float* __restrict__ x,
                            const float* __restrict__ agg,
                            const float* __restrict__ packed,
                            const float* __restrict__ b2,
                            float* __restrict__ s_rel,
                            float* __restrict__ out) {
    int n = blockIdx.x * blockDim.x + threadIdx.x;
    if (n >= N_NODES) return;
    float4 xv = reinterpret_cast<const float4*>(x)[n];
    float4 av = reinterpret_cast<const float4*>(agg)[n];
    const float4* pw = reinterpret_cast<const float4*>(packed);
    float srel = 0.f, sroot = 0.f;
#pragma unroll 4
    for (int j = 0; j < HIDDEN; ++j) {
        float4 wr = pw[j * 3 + 0];
        float4 wo = pw[j * 3 + 1];
        float4 wb = pw[j * 3 + 2];
        float pre = wb.x
                  + av.x * wr.x + av.y * wr.y + av.z * wr.z + av.w * wr.w
                  + xv.x * wo.x + xv.y * wo.y + xv.z * wo.z + xv.w * wo.w;
        float h = fmaxf(pre, 0.f);
        srel  += h * wb.y;
        sroot += h * wb.z;
    }
    s_rel[n] = srel;
    out[n]   = sroot + b2[0];
}

__global__ void scatter2_legacy(const int* __restrict__ ei, const float* __restrict__ ea,
                                const float* __restrict__ s_rel, float* __restrict__ out) {
    int e = blockIdx.x * blockDim.x + threadIdx.x;
    if (e >= N_EDGES) return;
    atomicAdd(&out[ei[N_EDGES + e]], s_rel[ei[e]] * ea[e]);
}

extern "C" void kernel_launch(void* const* d_in, const int* in_sizes, int n_in,
                              void* d_out, int out_size, void* d_ws, size_t ws_size,
                              hipStream_t stream) {
    const float* x       = (const float*)d_in[0];
    const int*   ei      = (const int*)  d_in[1];
    const float* ea      = (const float*)d_in[2];
    const float* W1_rel  = (const float*)d_in[3];
    const float* b1      = (const float*)d_in[4];
    const float* W1_root = (const float*)d_in[5];
    const float* W2_rel  = (const float*)d_in[6];
    const float* b2      = (const float*)d_in[7];
    const float* W2_root = (const float*)d_in[8];
    float* out = (float*)d_out;
    char*  ws  = (char*)d_ws;

    // ws layout: packed [1536 f] | s_rel [N f] | cursor [256 i] | recs [NBKT*CAPW u2]
    float* packed = (float*)ws;
    float* s_rel  = packed + 1536;
    int*   cursor = (int*)(s_rel + N_NODES);
    uint2* recs   = (uint2*)((char*)cursor + 1024);
    const size_t head = 1536 * 4 + (size_t)N_NODES * 4 + 1024;

    auto launch_coop = [&](auto cap_tag) {
        constexpr int CAPW = decltype(cap_tag)::value;
        void* args[] = {
            (void*)&ei, (void*)&ea, (void*)&x,
            (void*)&W1_rel, (void*)&b1, (void*)&W1_root,
            (void*)&W2_rel, (void*)&b2, (void*)&W2_root,
            (void*)&packed, (void*)&cursor, (void*)&recs,
            (void*)&s_rel, (void*)&out,
        };
        hipLaunchCooperativeKernel((void*)&mega_kernel<CAPW>,
                                   dim3(NBKT), dim3(GTHR), args, 0, stream);
    };

    if (ws_size >= head + (size_t)NBKT * 4096 * sizeof(uint2)) {
        launch_coop(std::integral_constant<int, 4096>{});
    } else if (ws_size >= head + (size_t)NBKT * 3072 * sizeof(uint2)) {
        launch_coop(std::integral_constant<int, 3072>{});
    } else {
        // Legacy global-atomic path; agg array lives where recs would.
        float* agg = (float*)recs;
        dim3 grdE((N_EDGES + 255) / 256);
        dim3 grdN((N_NODES + 255) / 256);
        prep_legacy<<<1, 256, 0, stream>>>(cursor, W1_rel, b1, W1_root,
                                           W2_rel, W2_root, packed);
        hipMemsetAsync(agg, 0, (size_t)N_NODES * 4 * sizeof(float), stream);
        scatter1_legacy<<<grdE, 256, 0, stream>>>(ei, ea, x, agg);
        node_legacy<<<grdN, 256, 0, stream>>>(x, agg, packed, b2, s_rel, out);
        scatter2_legacy<<<grdE, 256, 0, stream>>>(ei, ea, s_rel, out);
    }
}

// Round 7
// 56.854 us; speedup vs baseline: 4.5332x; 4.5332x over previous
//
#include <hip/hip_runtime.h>

#define N_NODES 100000
#define N_EDGES 640000
#define HIDDEN  128

// Deterministic bucketed partition (no global atomics anywhere).
#define NB    200              // nodes per bucket
#define NBKT  500              // buckets; NB*NBKT == N_NODES
#define PB    125              // partition blocks
#define PT    512              // partition threads
#define EPT   10               // edges/thread: PB*PT*EPT == N_EDGES
#define BLK_RECS (PT * EPT)    // 5120 records per partition block

// ---------------------------------------------------------------------------
// Partition (+weight prep in block 0).
// Each block LDS-sorts its 5120 edge records by dst bucket, then:
//   - streams them to its OWN region recs[pb*5120..] (fully coalesced)
//   - writes per-bucket start offsets to bs[bkt*PB + pb] (bs row-major by
//     bucket so consumers read contiguous rows); sentinel row NBKT = 5120.
// Record: x = src | (dst_local << 17), y = w bits.
// ---------------------------------------------------------------------------
__global__ __launch_bounds__(PT) void partition_kernel(
    const int* __restrict__ ei, const float* __restrict__ ea,
    const float* __restrict__ W1_rel, const float* __restrict__ b1,
    const float* __restrict__ W1_root, const float* __restrict__ W2_rel,
    const float* __restrict__ W2_root,
    uint2* __restrict__ recs, int* __restrict__ bs,
    float* __restrict__ packed) {
    const int tid = threadIdx.x;
    const int pb  = blockIdx.x;

    // Weight prep (consumed only by later dispatches):
    //   packed[j*12+0..3]=W1_rel[., j], +4..7=W1_root[., j],
    //   +8..10 = b1[j], W2_rel[j], W2_root[j]
    if (pb == 0 && tid < HIDDEN) {
        float* p = packed + tid * 12;
#pragma unroll
        for (int k = 0; k < 4; ++k) p[k]     = W1_rel[k * HIDDEN + tid];
#pragma unroll
        for (int k = 0; k < 4; ++k) p[4 + k] = W1_root[k * HIDDEN + tid];
        p[8]  = b1[tid];
        p[9]  = W2_rel[tid];
        p[10] = W2_root[tid];
        p[11] = 0.f;
    }

    __shared__ int   hist[NBKT];
    __shared__ int   start[NBKT];
    __shared__ int   wcur[NBKT];
    __shared__ uint2 srec[BLK_RECS];   // 40 KB

    for (int i = tid; i < NBKT; i += PT) hist[i] = 0;
    __syncthreads();

    int   dsts[EPT];
    int   srcs[EPT];
    float wts[EPT];
    const int e0 = pb * BLK_RECS + tid;
#pragma unroll
    for (int k = 0; k < EPT; ++k) {
        int e = e0 + k * PT;
        srcs[k] = ei[e];
        dsts[k] = ei[N_EDGES + e];
        wts[k]  = ea[e];
        atomicAdd(&hist[dsts[k] / NB], 1);
    }
    __syncthreads();

    // Single-wave exclusive scan of hist -> start/wcur.
    if (tid < 64) {
        int base = 0;
        for (int c = 0; c < NBKT; c += 64) {
            int idx = c + tid;
            int v = (idx < NBKT) ? hist[idx] : 0;
            int orig = v;
#pragma unroll
            for (int off = 1; off < 64; off <<= 1) {
                int t = __shfl_up(v, off);
                if (tid >= off) v += t;
            }
            if (idx < NBKT) {
                start[idx] = base + v - orig;
                wcur[idx]  = base + v - orig;
            }
            base += __shfl(v, 63);
        }
    }
    __syncthreads();

    // Publish per-bucket offsets (column pb of bs).
    for (int i = tid; i < NBKT; i += PT) bs[i * PB + pb] = start[i];
    if (tid == 0) bs[NBKT * PB + pb] = BLK_RECS;

    // Scatter records into LDS in bucket-sorted order.
#pragma unroll
    for (int k = 0; k < EPT; ++k) {
        int d  = dsts[k];
        int b  = d / NB;
        int dl = d - b * NB;
        int slot = atomicAdd(&wcur[b], 1);
        srec[slot] = make_uint2((unsigned)srcs[k] | ((unsigned)dl << 17),
                                __float_as_uint(wts[k]));
    }
    __syncthreads();

    // Stream the sorted block to global — perfectly coalesced.
    uint2* dst = recs + (size_t)pb * BLK_RECS;
    for (int j = tid; j < BLK_RECS; j += PT) dst[j] = srec[j];
}

// ---------------------------------------------------------------------------
// Build the flattened run index for bucket b: rbase[pb] (global rec offset of
// this bucket's run in block pb) and pfx[] (prefix of run lengths). Shared by
// fused/agg2.
// ---------------------------------------------------------------------------
__device__ __forceinline__ int build_runs(const int* __restrict__ bs, int b,
                                          int* rbase, int* lenA, int* pfx) {
    const int tid = threadIdx.x;
    if (tid < PB) {
        int s = bs[b * PB + tid];            // coalesced row read
        int e = bs[(b + 1) * PB + tid];      // next row (sentinel-safe)
        rbase[tid] = tid * BLK_RECS + s;
        lenA[tid]  = e - s;
    }
    __syncthreads();
    if (tid < 64) {
        int base = 0;
        for (int c = 0; c < PB; c += 64) {
            int idx = c + tid;
            int v = (idx < PB) ? lenA[idx] : 0;
            int orig = v;
#pragma unroll
            for (int off = 1; off < 64; off <<= 1) {
                int t = __shfl_up(v, off);
                if (tid >= off) v += t;
            }
            if (idx < PB) pfx[idx] = base + v - orig;
            base += __shfl(v, 63);
        }
        if (tid == 0) pfx[PB] = base;
    }
    __syncthreads();
    return pfx[PB];
}

__device__ __forceinline__ int find_run(const int* pfx, int f) {
    int lo = 0, hi = PB;                     // pfx[lo] <= f < pfx[hi]
    while (hi - lo > 1) {
        int m = (lo + hi) >> 1;
        if (pfx[m] <= f) lo = m; else hi = m;
    }
    return lo;
}

// ---------------------------------------------------------------------------
// FUSED layer-1 aggregation + per-node MLP for bucket b = blockIdx.x.
// ---------------------------------------------------------------------------
__global__ __launch_bounds__(256) void fused_kernel(
    const uint2* __restrict__ recs, const int* __restrict__ bs,
    const float* __restrict__ x, const float* __restrict__ packed,
    const float* __restrict__ b2, float* __restrict__ s_rel,
    float* __restrict__ out) {
    __shared__ float accf[NB * 4];
    __shared__ int   rbase[PB];
    __shared__ int   lenA[PB];
    __shared__ int   pfx[PB + 1];

    const int tid = threadIdx.x;
    const int b   = blockIdx.x;

    for (int i = tid; i < NB * 4; i += 256) accf[i] = 0.f;
    const int cnt = build_runs(bs, b, rbase, lenA, pfx);

    for (int f = tid; f < cnt; f += 256) {
        int run = find_run(pfx, f);
        uint2 rec = recs[(size_t)rbase[run] + (f - pfx[run])];
        int src = rec.x & 0x1FFFF;
        int dl  = rec.x >> 17;
        float w = __uint_as_float(rec.y);
        float4 xv = reinterpret_cast<const float4*>(x)[src];
        atomicAdd(&accf[dl * 4 + 0], xv.x * w);
        atomicAdd(&accf[dl * 4 + 1], xv.y * w);
        atomicAdd(&accf[dl * 4 + 2], xv.z * w);
        atomicAdd(&accf[dl * 4 + 3], xv.w * w);
    }
    __syncthreads();

    if (tid >= NB) return;
    const int n = b * NB + tid;

    float4 xv = reinterpret_cast<const float4*>(x)[n];
    float4 av = make_float4(accf[tid * 4 + 0], accf[tid * 4 + 1],
                            accf[tid * 4 + 2], accf[tid * 4 + 3]);

    const float4* pw = reinterpret_cast<const float4*>(packed);
    float srel = 0.f, sroot = 0.f;
#pragma unroll 4
    for (int j = 0; j < HIDDEN; ++j) {
        float4 wr = pw[j * 3 + 0];   // W1_rel[0..3][j]
        float4 wo = pw[j * 3 + 1];   // W1_root[0..3][j]
        float4 wb = pw[j * 3 + 2];   // b1, W2_rel, W2_root, pad
        float pre = wb.x
                  + av.x * wr.x + av.y * wr.y + av.z * wr.z + av.w * wr.w
                  + xv.x * wo.x + xv.y * wo.y + xv.z * wo.z + xv.w * wo.w;
        float h = fmaxf(pre, 0.f);
        srel  += h * wb.y;
        sroot += h * wb.z;
    }
    s_rel[n] = srel;
    out[n]   = sroot + b2[0];
}

// ---------------------------------------------------------------------------
// Layer-2 scalar aggregation for bucket b; non-atomic out +=.
// ---------------------------------------------------------------------------
__global__ __launch_bounds__(256) void agg2_kernel(
    const uint2* __restrict__ recs, const int* __restrict__ bs,
    const float* __restrict__ s_rel, float* __restrict__ out) {
    __shared__ float acc[NB];
    __shared__ int   rbase[PB];
    __shared__ int   lenA[PB];
    __shared__ int   pfx[PB + 1];

    const int tid = threadIdx.x;
    const int b   = blockIdx.x;

    for (int i = tid; i < NB; i += 256) acc[i] = 0.f;
    const int cnt = build_runs(bs, b, rbase, lenA, pfx);

    for (int f = tid; f < cnt; f += 256) {
        int run = find_run(pfx, f);
        uint2 rec = recs[(size_t)rbase[run] + (f - pfx[run])];
        int src = rec.x & 0x1FFFF;
        int dl  = rec.x >> 17;
        atomicAdd(&acc[dl], s_rel[src] * __uint_as_float(rec.y));
    }
    __syncthreads();

    if (tid < NB)
        out[b * NB + tid] += acc[tid];
}

// ---------------------------------------------------------------------------
// Legacy fallback (ws too small): direct global-atomic path.
// ---------------------------------------------------------------------------
__global__ void prep_legacy(const float* __restrict__ W1_rel,
                            const float* __restrict__ b1,
                            const float* __restrict__ W1_root,
                            const float* __restrict__ W2_rel,
                            const float* __restrict__ W2_root,
                            float* __restrict__ packed) {
    int t = threadIdx.x;
    if (t < HIDDEN) {
        float* p = packed + t * 12;
#pragma unroll
        for (int k = 0; k < 4; ++k) p[k]     = W1_rel[k * HIDDEN + t];
#pragma unroll
        for (int k = 0; k < 4; ++k) p[4 + k] = W1_root[k * HIDDEN + t];
        p[8]  = b1[t];
        p[9]  = W2_rel[t];
        p[10] = W2_root[t];
        p[11] = 0.f;
    }
}

__global__ void scatter1_legacy(const int* __restrict__ ei, const float* __restrict__ ea,
                                const float* __restrict__ x, float* __restrict__ agg) {
    int e = blockIdx.x * blockDim.x + threadIdx.x;
    if (e >= N_EDGES) return;
    int src = ei[e], dst = ei[N_EDGES + e];
    float w = ea[e];
    float4 xv = reinterpret_cast<const float4*>(x)[src];
    atomicAdd(&agg[dst * 4 + 0], xv.x * w);
    atomicAdd(&agg[dst * 4 + 1], xv.y * w);
    atomicAdd(&agg[dst * 4 + 2], xv.z * w);
    atomicAdd(&agg[dst * 4 + 3], xv.w * w);
}

__global__ __launch_bounds__(256) void node_legacy(const float* __restrict__ x,
                            const float* __restrict__ agg,
                            const float* __restrict__ packed,
                            const float* __restrict__ b2,
                            float* __restrict__ s_rel,
                            float* __restrict__ out) {
    int n = blockIdx.x * blockDim.x + threadIdx.x;
    if (n >= N_NODES) return;
    float4 xv = reinterpret_cast<const float4*>(x)[n];
    float4 av = reinterpret_cast<const float4*>(agg)[n];
    const float4* pw = reinterpret_cast<const float4*>(packed);
    float srel = 0.f, sroot = 0.f;
#pragma unroll 4
    for (int j = 0; j < HIDDEN; ++j) {
        float4 wr = pw[j * 3 + 0];
        float4 wo = pw[j * 3 + 1];
        float4 wb = pw[j * 3 + 2];
        float pre = wb.x
                  + av.x * wr.x + av.y * wr.y + av.z * wr.z + av.w * wr.w
                  + xv.x * wo.x + xv.y * wo.y + xv.z * wo.z + xv.w * wo.w;
        float h = fmaxf(pre, 0.f);
        srel  += h * wb.y;
        sroot += h * wb.z;
    }
    s_rel[n] = srel;
    out[n]   = sroot + b2[0];
}

__global__ void scatter2_legacy(const int* __restrict__ ei, const float* __restrict__ ea,
                                const float* __restrict__ s_rel, float* __restrict__ out) {
    int e = blockIdx.x * blockDim.x + threadIdx.x;
    if (e >= N_EDGES) return;
    atomicAdd(&out[ei[N_EDGES + e]], s_rel[ei[e]] * ea[e]);
}

extern "C" void kernel_launch(void* const* d_in, const int* in_sizes, int n_in,
                              void* d_out, int out_size, void* d_ws, size_t ws_size,
                              hipStream_t stream) {
    const float* x       = (const float*)d_in[0];
    const int*   ei      = (const int*)  d_in[1];
    const float* ea      = (const float*)d_in[2];
    const float* W1_rel  = (const float*)d_in[3];
    const float* b1      = (const float*)d_in[4];
    const float* W1_root = (const float*)d_in[5];
    const float* W2_rel  = (const float*)d_in[6];
    const float* b2      = (const float*)d_in[7];
    const float* W2_root = (const float*)d_in[8];
    float* out = (float*)d_out;
    char*  ws  = (char*)d_ws;

    // ws layout: packed [1536 f] | s_rel [N f] | bs [(NBKT+1)*PB i] | recs [E u2]
    float* packed = (float*)ws;
    float* s_rel  = packed + 1536;
    int*   bs     = (int*)(s_rel + N_NODES);
    uint2* recs   = (uint2*)(bs + (NBKT + 1) * PB);
    const size_t need = 1536 * 4 + (size_t)N_NODES * 4 +
                        (size_t)(NBKT + 1) * PB * 4 + (size_t)N_EDGES * 8;

    if (ws_size >= need) {
        partition_kernel<<<PB, PT, 0, stream>>>(ei, ea, W1_rel, b1, W1_root,
                                                W2_rel, W2_root, recs, bs, packed);
        fused_kernel<<<NBKT, 256, 0, stream>>>(recs, bs, x, packed, b2, s_rel, out);
        agg2_kernel<<<NBKT, 256, 0, stream>>>(recs, bs, s_rel, out);
    } else {
        // Legacy global-atomic path; agg array lives where recs would.
        float* agg = (float*)recs;
        dim3 grdE((N_EDGES + 255) / 256);
        dim3 grdN((N_NODES + 255) / 256);
        prep_legacy<<<1, 256, 0, stream>>>(W1_rel, b1, W1_root, W2_rel, W2_root, packed);
        hipMemsetAsync(agg, 0, (size_t)N_NODES * 4 * sizeof(float), stream);
        scatter1_legacy<<<grdE, 256, 0, stream>>>(ei, ea, x, agg);
        node_legacy<<<grdN, 256, 0, stream>>>(x, agg, packed, b2, s_rel, out);
        scatter2_legacy<<<grdE, 256, 0, stream>>>(ei, ea, s_rel, out);
    }
}

// Round 8
// 53.684 us; speedup vs baseline: 4.8008x; 1.0590x over previous
//
#include <hip/hip_runtime.h>

#define N_NODES 100000
#define N_EDGES 640000
#define HIDDEN  128

// Deterministic bucketed partition (no global atomics anywhere).
#define NB    200              // nodes per bucket
#define NBKT  500              // buckets; NB*NBKT == N_NODES
#define PB    250              // partition blocks (one per CU, roughly)
#define PT    256              // partition threads
#define EPT   10               // edges/thread: PB*PT*EPT == N_EDGES
#define BLK_RECS (PT * EPT)    // 2560 records per partition block
#define RUNOF_CAP 2560         // run_of table size (>= 20 sigma above mean cnt)

// ---------------------------------------------------------------------------
// Partition (+weight prep in block 0).
// Each block LDS-sorts its 2560 edge records by dst bucket, then:
//   - streams them to its OWN region recs[pb*2560..] (fully coalesced)
//   - writes per-bucket start offsets to bs[bkt*PB + pb]; sentinel row = 2560.
// Record: x = src | (dst_local << 17), y = w bits.
// ---------------------------------------------------------------------------
__global__ __launch_bounds__(PT) void partition_kernel(
    const int* __restrict__ ei, const float* __restrict__ ea,
    const float* __restrict__ W1_rel, const float* __restrict__ b1,
    const float* __restrict__ W1_root, const float* __restrict__ W2_rel,
    const float* __restrict__ W2_root,
    uint2* __restrict__ recs, int* __restrict__ bs,
    float* __restrict__ packed) {
    const int tid = threadIdx.x;
    const int pb  = blockIdx.x;

    // Weight prep (consumed only by later dispatches):
    if (pb == 0 && tid < HIDDEN) {
        float* p = packed + tid * 12;
#pragma unroll
        for (int k = 0; k < 4; ++k) p[k]     = W1_rel[k * HIDDEN + tid];
#pragma unroll
        for (int k = 0; k < 4; ++k) p[4 + k] = W1_root[k * HIDDEN + tid];
        p[8]  = b1[tid];
        p[9]  = W2_rel[tid];
        p[10] = W2_root[tid];
        p[11] = 0.f;
    }

    __shared__ int   hist[NBKT];
    __shared__ int   start[NBKT];
    __shared__ int   wcur[NBKT];
    __shared__ uint2 srec[BLK_RECS];   // 20 KB

    for (int i = tid; i < NBKT; i += PT) hist[i] = 0;
    __syncthreads();

    int   dsts[EPT];
    int   srcs[EPT];
    float wts[EPT];
    const int e0 = pb * BLK_RECS + tid;
#pragma unroll
    for (int k = 0; k < EPT; ++k) {
        int e = e0 + k * PT;
        srcs[k] = ei[e];
        dsts[k] = ei[N_EDGES + e];
        wts[k]  = ea[e];
        atomicAdd(&hist[dsts[k] / NB], 1);
    }
    __syncthreads();

    // Single-wave exclusive scan of hist -> start/wcur.
    if (tid < 64) {
        int base = 0;
        for (int c = 0; c < NBKT; c += 64) {
            int idx = c + tid;
            int v = (idx < NBKT) ? hist[idx] : 0;
            int orig = v;
#pragma unroll
            for (int off = 1; off < 64; off <<= 1) {
                int t = __shfl_up(v, off);
                if (tid >= off) v += t;
            }
            if (idx < NBKT) {
                start[idx] = base + v - orig;
                wcur[idx]  = base + v - orig;
            }
            base += __shfl(v, 63);
        }
    }
    __syncthreads();

    // Publish per-bucket offsets (column pb of bs).
    for (int i = tid; i < NBKT; i += PT) bs[i * PB + pb] = start[i];
    if (tid == 0) bs[NBKT * PB + pb] = BLK_RECS;

    // Scatter records into LDS in bucket-sorted order.
#pragma unroll
    for (int k = 0; k < EPT; ++k) {
        int d  = dsts[k];
        int b  = d / NB;
        int dl = d - b * NB;
        int slot = atomicAdd(&wcur[b], 1);
        srec[slot] = make_uint2((unsigned)srcs[k] | ((unsigned)dl << 17),
                                __float_as_uint(wts[k]));
    }
    __syncthreads();

    // Stream the sorted block to global — fully coalesced.
    uint2* dst = recs + (size_t)pb * BLK_RECS;
    for (int j = tid; j < BLK_RECS; j += PT) dst[j] = srec[j];
}

// ---------------------------------------------------------------------------
// Shared consumer indexing for bucket b:
//   rbase[r] = global rec offset of run r, pfx[] = prefix of run lengths,
//   run_of[f] = run containing flattened index f (direct lookup, no search).
// ---------------------------------------------------------------------------
__device__ __forceinline__ int find_run(const int* pfx, int f) {
    int lo = 0, hi = PB;
    while (hi - lo > 1) {
        int m = (lo + hi) >> 1;
        if (pfx[m] <= f) lo = m; else hi = m;
    }
    return lo;
}

__device__ __forceinline__ int build_runs(const int* __restrict__ bs, int b,
                                          int* rbase, int* pfx,
                                          short* run_of) {
    const int tid = threadIdx.x;
    __shared__ int lenA[PB];
    if (tid < PB) {
        int s = bs[b * PB + tid];            // coalesced row read
        int e = bs[(b + 1) * PB + tid];      // next row (sentinel-safe)
        rbase[tid] = tid * BLK_RECS + s;
        lenA[tid]  = e - s;
    }
    __syncthreads();
    if (tid < 64) {
        int base = 0;
        for (int c = 0; c < PB; c += 64) {
            int idx = c + tid;
            int v = (idx < PB) ? lenA[idx] : 0;
            int orig = v;
#pragma unroll
            for (int off = 1; off < 64; off <<= 1) {
                int t = __shfl_up(v, off);
                if (tid >= off) v += t;
            }
            if (idx < PB) pfx[idx] = base + v - orig;
            base += __shfl(v, 63);
        }
        if (tid == 0) pfx[PB] = base;
    }
    __syncthreads();
    // Fill the run_of lookup (each thread writes its run's ~5 entries).
    if (tid < PB) {
        int s = pfx[tid];
        int e = pfx[tid + 1];
        if (e > RUNOF_CAP) e = RUNOF_CAP;
        for (int j = s; j < e; ++j) run_of[j] = (short)tid;
    }
    __syncthreads();
    return pfx[PB];
}

// ---------------------------------------------------------------------------
// FUSED layer-1 aggregation + per-node MLP for bucket b = blockIdx.x.
// ---------------------------------------------------------------------------
__global__ __launch_bounds__(256) void fused_kernel(
    const uint2* __restrict__ recs, const int* __restrict__ bs,
    const float* __restrict__ x, const float* __restrict__ packed,
    const float* __restrict__ b2, float* __restrict__ s_rel,
    float* __restrict__ out) {
    __shared__ float accf[NB * 4];
    __shared__ int   rbase[PB];
    __shared__ int   pfx[PB + 1];
    __shared__ short run_of[RUNOF_CAP];

    const int tid = threadIdx.x;
    const int b   = blockIdx.x;

    for (int i = tid; i < NB * 4; i += 256) accf[i] = 0.f;
    const int cnt = build_runs(bs, b, rbase, pfx, run_of);

    for (int f = tid; f < cnt; f += 256) {
        int run = (f < RUNOF_CAP) ? (int)run_of[f] : find_run(pfx, f);
        uint2 rec = recs[(size_t)rbase[run] + (f - pfx[run])];
        int src = rec.x & 0x1FFFF;
        int dl  = rec.x >> 17;
        float w = __uint_as_float(rec.y);
        float4 xv = reinterpret_cast<const float4*>(x)[src];
        atomicAdd(&accf[dl * 4 + 0], xv.x * w);
        atomicAdd(&accf[dl * 4 + 1], xv.y * w);
        atomicAdd(&accf[dl * 4 + 2], xv.z * w);
        atomicAdd(&accf[dl * 4 + 3], xv.w * w);
    }
    __syncthreads();

    if (tid >= NB) return;
    const int n = b * NB + tid;

    float4 xv = reinterpret_cast<const float4*>(x)[n];
    float4 av = make_float4(accf[tid * 4 + 0], accf[tid * 4 + 1],
                            accf[tid * 4 + 2], accf[tid * 4 + 3]);

    const float4* pw = reinterpret_cast<const float4*>(packed);
    float srel = 0.f, sroot = 0.f;
#pragma unroll 4
    for (int j = 0; j < HIDDEN; ++j) {
        float4 wr = pw[j * 3 + 0];   // W1_rel[0..3][j]
        float4 wo = pw[j * 3 + 1];   // W1_root[0..3][j]
        float4 wb = pw[j * 3 + 2];   // b1, W2_rel, W2_root, pad
        float pre = wb.x
                  + av.x * wr.x + av.y * wr.y + av.z * wr.z + av.w * wr.w
                  + xv.x * wo.x + xv.y * wo.y + xv.z * wo.z + xv.w * wo.w;
        float h = fmaxf(pre, 0.f);
        srel  += h * wb.y;
        sroot += h * wb.z;
    }
    s_rel[n] = srel;
    out[n]   = sroot + b2[0];
}

// ---------------------------------------------------------------------------
// Layer-2 scalar aggregation for bucket b; non-atomic out +=.
// ---------------------------------------------------------------------------
__global__ __launch_bounds__(256) void agg2_kernel(
    const uint2* __restrict__ recs, const int* __restrict__ bs,
    const float* __restrict__ s_rel, float* __restrict__ out) {
    __shared__ float acc[NB];
    __shared__ int   rbase[PB];
    __shared__ int   pfx[PB + 1];
    __shared__ short run_of[RUNOF_CAP];

    const int tid = threadIdx.x;
    const int b   = blockIdx.x;

    for (int i = tid; i < NB; i += 256) acc[i] = 0.f;
    const int cnt = build_runs(bs, b, rbase, pfx, run_of);

    for (int f = tid; f < cnt; f += 256) {
        int run = (f < RUNOF_CAP) ? (int)run_of[f] : find_run(pfx, f);
        uint2 rec = recs[(size_t)rbase[run] + (f - pfx[run])];
        int src = rec.x & 0x1FFFF;
        int dl  = rec.x >> 17;
        atomicAdd(&acc[dl], s_rel[src] * __uint_as_float(rec.y));
    }
    __syncthreads();

    if (tid < NB)
        out[b * NB + tid] += acc[tid];
}

// ---------------------------------------------------------------------------
// Legacy fallback (ws too small): direct global-atomic path.
// ---------------------------------------------------------------------------
__global__ void prep_legacy(const float* __restrict__ W1_rel,
                            const float* __restrict__ b1,
                            const float* __restrict__ W1_root,
                            const float* __restrict__ W2_rel,
                            const float* __restrict__ W2_root,
                            float* __restrict__ packed) {
    int t = threadIdx.x;
    if (t < HIDDEN) {
        float* p = packed + t * 12;
#pragma unroll
        for (int k = 0; k < 4; ++k) p[k]     = W1_rel[k * HIDDEN + t];
#pragma unroll
        for (int k = 0; k < 4; ++k) p[4 + k] = W1_root[k * HIDDEN + t];
        p[8]  = b1[t];
        p[9]  = W2_rel[t];
        p[10] = W2_root[t];
        p[11] = 0.f;
    }
}

__global__ void scatter1_legacy(const int* __restrict__ ei, const float* __restrict__ ea,
                                const float* __restrict__ x, float* __restrict__ agg) {
    int e = blockIdx.x * blockDim.x + threadIdx.x;
    if (e >= N_EDGES) return;
    int src = ei[e], dst = ei[N_EDGES + e];
    float w = ea[e];
    float4 xv = reinterpret_cast<const float4*>(x)[src];
    atomicAdd(&agg[dst * 4 + 0], xv.x * w);
    atomicAdd(&agg[dst * 4 + 1], xv.y * w);
    atomicAdd(&agg[dst * 4 + 2], xv.z * w);
    atomicAdd(&agg[dst * 4 + 3], xv.w * w);
}

__global__ __launch_bounds__(256) void node_legacy(const float* __restrict__ x,
                            const float* __restrict__ agg,
                            const float* __restrict__ packed,
                            const float* __restrict__ b2,
                            float* __restrict__ s_rel,
                            float* __restrict__ out) {
    int n = blockIdx.x * blockDim.x + threadIdx.x;
    if (n >= N_NODES) return;
    float4 xv = reinterpret_cast<const float4*>(x)[n];
    float4 av = reinterpret_cast<const float4*>(agg)[n];
    const float4* pw = reinterpret_cast<const float4*>(packed);
    float srel = 0.f, sroot = 0.f;
#pragma unroll 4
    for (int j = 0; j < HIDDEN; ++j) {
        float4 wr = pw[j * 3 + 0];
        float4 wo = pw[j * 3 + 1];
        float4 wb = pw[j * 3 + 2];
        float pre = wb.x
                  + av.x * wr.x + av.y * wr.y + av.z * wr.z + av.w * wr.w
                  + xv.x * wo.x + xv.y * wo.y + xv.z * wo.z + xv.w * wo.w;
        float h = fmaxf(pre, 0.f);
        srel  += h * wb.y;
        sroot += h * wb.z;
    }
    s_rel[n] = srel;
    out[n]   = sroot + b2[0];
}

__global__ void scatter2_legacy(const int* __restrict__ ei, const float* __restrict__ ea,
                                const float* __restrict__ s_rel, float* __restrict__ out) {
    int e = blockIdx.x * blockDim.x + threadIdx.x;
    if (e >= N_EDGES) return;
    atomicAdd(&out[ei[N_EDGES + e]], s_rel[ei[e]] * ea[e]);
}

extern "C" void kernel_launch(void* const* d_in, const int* in_sizes, int n_in,
                              void* d_out, int out_size, void* d_ws, size_t ws_size,
                              hipStream_t stream) {
    const float* x       = (const float*)d_in[0];
    const int*   ei      = (const int*)  d_in[1];
    const float* ea      = (const float*)d_in[2];
    const float* W1_rel  = (const float*)d_in[3];
    const float* b1      = (const float*)d_in[4];
    const float* W1_root = (const float*)d_in[5];
    const float* W2_rel  = (const float*)d_in[6];
    const float* b2      = (const float*)d_in[7];
    const float* W2_root = (const float*)d_in[8];
    float* out = (float*)d_out;
    char*  ws  = (char*)d_ws;

    // ws layout: packed [1536 f] | s_rel [N f] | bs [(NBKT+1)*PB i] | recs [E u2]
    float* packed = (float*)ws;
    float* s_rel  = packed + 1536;
    int*   bs     = (int*)(s_rel + N_NODES);
    uint2* recs   = (uint2*)(bs + (NBKT + 1) * PB);
    const size_t need = 1536 * 4 + (size_t)N_NODES * 4 +
                        (size_t)(NBKT + 1) * PB * 4 + (size_t)N_EDGES * 8;

    if (ws_size >= need) {
        partition_kernel<<<PB, PT, 0, stream>>>(ei, ea, W1_rel, b1, W1_root,
                                                W2_rel, W2_root, recs, bs, packed);
        fused_kernel<<<NBKT, 256, 0, stream>>>(recs, bs, x, packed, b2, s_rel, out);
        agg2_kernel<<<NBKT, 256, 0, stream>>>(recs, bs, s_rel, out);
    } else {
        // Legacy global-atomic path; agg array lives where recs would.
        float* agg = (float*)recs;
        dim3 grdE((N_EDGES + 255) / 256);
        dim3 grdN((N_NODES + 255) / 256);
        prep_legacy<<<1, 256, 0, stream>>>(W1_rel, b1, W1_root, W2_rel, W2_root, packed);
        hipMemsetAsync(agg, 0, (size_t)N_NODES * 4 * sizeof(float), stream);
        scatter1_legacy<<<grdE, 256, 0, stream>>>(ei, ea, x, agg);
        node_legacy<<<grdN, 256, 0, stream>>>(x, agg, packed, b2, s_rel, out);
        scatter2_legacy<<<grdE, 256, 0, stream>>>(ei, ea, s_rel, out);
    }
}

// Round 9
// 53.254 us; speedup vs baseline: 4.8396x; 1.0081x over previous
//
#include <hip/hip_runtime.h>

#define N_NODES 100000
#define N_EDGES 640000
#define HIDDEN  128

// Deterministic bucketed partition (no global atomics anywhere).
#define NB    200              // nodes per bucket
#define NBKT  500              // buckets; NB*NBKT == N_NODES
#define PB    250              // partition blocks
#define PT    512              // partition threads (8 waves/block)
#define EPT   5                // edges/thread: PB*PT*EPT == N_EDGES
#define BLK_RECS (PT * EPT)    // 2560 records per partition block
#define CT    512              // consumer threads (8 waves/block)
#define RUNOF_CAP 2560         // run_of table size (>> any realistic cnt)

// ---------------------------------------------------------------------------
// Partition (+weight prep in block 0).
// Each block LDS-sorts its 2560 edge records by dst bucket, then:
//   - streams them to its OWN region recs[pb*2560..] (fully coalesced)
//   - writes per-bucket start offsets to bs[bkt*PB + pb]; sentinel row = 2560.
// Record: x = src | (dst_local << 17), y = w bits.
// ---------------------------------------------------------------------------
__global__ __launch_bounds__(PT) void partition_kernel(
    const int* __restrict__ ei, const float* __restrict__ ea,
    const float* __restrict__ W1_rel, const float* __restrict__ b1,
    const float* __restrict__ W1_root, const float* __restrict__ W2_rel,
    const float* __restrict__ W2_root,
    uint2* __restrict__ recs, int* __restrict__ bs,
    float* __restrict__ packed) {
    const int tid = threadIdx.x;
    const int pb  = blockIdx.x;

    // Weight prep (consumed only by later dispatches):
    if (pb == 0 && tid < HIDDEN) {
        float* p = packed + tid * 12;
#pragma unroll
        for (int k = 0; k < 4; ++k) p[k]     = W1_rel[k * HIDDEN + tid];
#pragma unroll
        for (int k = 0; k < 4; ++k) p[4 + k] = W1_root[k * HIDDEN + tid];
        p[8]  = b1[tid];
        p[9]  = W2_rel[tid];
        p[10] = W2_root[tid];
        p[11] = 0.f;
    }

    __shared__ int   hist[NBKT];
    __shared__ int   start[NBKT];
    __shared__ int   wcur[NBKT];
    __shared__ uint2 srec[BLK_RECS];   // 20 KB

    for (int i = tid; i < NBKT; i += PT) hist[i] = 0;
    __syncthreads();

    int   dsts[EPT];
    int   srcs[EPT];
    float wts[EPT];
    const int e0 = pb * BLK_RECS + tid;
#pragma unroll
    for (int k = 0; k < EPT; ++k) {
        int e = e0 + k * PT;
        srcs[k] = ei[e];
        dsts[k] = ei[N_EDGES + e];
        wts[k]  = ea[e];
        atomicAdd(&hist[dsts[k] / NB], 1);
    }
    __syncthreads();

    // Single-wave exclusive scan of hist -> start/wcur.
    if (tid < 64) {
        int base = 0;
        for (int c = 0; c < NBKT; c += 64) {
            int idx = c + tid;
            int v = (idx < NBKT) ? hist[idx] : 0;
            int orig = v;
#pragma unroll
            for (int off = 1; off < 64; off <<= 1) {
                int t = __shfl_up(v, off);
                if (tid >= off) v += t;
            }
            if (idx < NBKT) {
                start[idx] = base + v - orig;
                wcur[idx]  = base + v - orig;
            }
            base += __shfl(v, 63);
        }
    }
    __syncthreads();

    // Publish per-bucket offsets (column pb of bs).
    for (int i = tid; i < NBKT; i += PT) bs[i * PB + pb] = start[i];
    if (tid == 0) bs[NBKT * PB + pb] = BLK_RECS;

    // Scatter records into LDS in bucket-sorted order.
#pragma unroll
    for (int k = 0; k < EPT; ++k) {
        int d  = dsts[k];
        int b  = d / NB;
        int dl = d - b * NB;
        int slot = atomicAdd(&wcur[b], 1);
        srec[slot] = make_uint2((unsigned)srcs[k] | ((unsigned)dl << 17),
                                __float_as_uint(wts[k]));
    }
    __syncthreads();

    // Stream the sorted block to global — fully coalesced.
    uint2* dst = recs + (size_t)pb * BLK_RECS;
    for (int j = tid; j < BLK_RECS; j += PT) dst[j] = srec[j];
}

// ---------------------------------------------------------------------------
// Shared consumer indexing for bucket b:
//   rbase[r] = global rec offset of run r, pfx[] = prefix of run lengths,
//   run_of[f] = run containing flattened index f (direct lookup, no search).
// ---------------------------------------------------------------------------
__device__ __forceinline__ int find_run(const int* pfx, int f) {
    int lo = 0, hi = PB;
    while (hi - lo > 1) {
        int m = (lo + hi) >> 1;
        if (pfx[m] <= f) lo = m; else hi = m;
    }
    return lo;
}

__device__ __forceinline__ int build_runs(const int* __restrict__ bs, int b,
                                          int* rbase, int* pfx,
                                          short* run_of) {
    const int tid = threadIdx.x;
    __shared__ int lenA[PB];
    if (tid < PB) {
        int s = bs[b * PB + tid];            // coalesced row read
        int e = bs[(b + 1) * PB + tid];      // next row (sentinel-safe)
        rbase[tid] = tid * BLK_RECS + s;
        lenA[tid]  = e - s;
    }
    __syncthreads();
    if (tid < 64) {
        int base = 0;
        for (int c = 0; c < PB; c += 64) {
            int idx = c + tid;
            int v = (idx < PB) ? lenA[idx] : 0;
            int orig = v;
#pragma unroll
            for (int off = 1; off < 64; off <<= 1) {
                int t = __shfl_up(v, off);
                if (tid >= off) v += t;
            }
            if (idx < PB) pfx[idx] = base + v - orig;
            base += __shfl(v, 63);
        }
        if (tid == 0) pfx[PB] = base;
    }
    __syncthreads();
    // Fill the run_of lookup (each thread writes its run's ~10 entries).
    if (tid < PB) {
        int s = pfx[tid];
        int e = pfx[tid + 1];
        if (e > RUNOF_CAP) e = RUNOF_CAP;
        for (int j = s; j < e; ++j) run_of[j] = (short)tid;
    }
    __syncthreads();
    return pfx[PB];
}

// ---------------------------------------------------------------------------
// FUSED layer-1 aggregation + per-node MLP for bucket b = blockIdx.x.
// Record loop: prefetch all (<=3) records to registers first (independent
// chains in flight), then gather x and accumulate.
// ---------------------------------------------------------------------------
__global__ __launch_bounds__(CT) void fused_kernel(
    const uint2* __restrict__ recs, const int* __restrict__ bs,
    const float* __restrict__ x, const float* __restrict__ packed,
    const float* __restrict__ b2, float* __restrict__ s_rel,
    float* __restrict__ out) {
    __shared__ float accf[NB * 4];
    __shared__ int   rbase[PB];
    __shared__ int   pfx[PB + 1];
    __shared__ short run_of[RUNOF_CAP];

    const int tid = threadIdx.x;
    const int b   = blockIdx.x;

    for (int i = tid; i < NB * 4; i += CT) accf[i] = 0.f;
    const int cnt = build_runs(bs, b, rbase, pfx, run_of);

    const int f0 = tid, f1 = tid + CT, f2 = tid + 2 * CT;
    uint2 r0, r1, r2;
    if (f0 < cnt) { int rn = run_of[f0]; r0 = recs[(size_t)rbase[rn] + (f0 - pfx[rn])]; }
    if (f1 < cnt) { int rn = run_of[f1]; r1 = recs[(size_t)rbase[rn] + (f1 - pfx[rn])]; }
    if (f2 < cnt) { int rn = run_of[f2]; r2 = recs[(size_t)rbase[rn] + (f2 - pfx[rn])]; }

    float4 xv0, xv1, xv2;
    if (f0 < cnt) xv0 = reinterpret_cast<const float4*>(x)[r0.x & 0x1FFFF];
    if (f1 < cnt) xv1 = reinterpret_cast<const float4*>(x)[r1.x & 0x1FFFF];
    if (f2 < cnt) xv2 = reinterpret_cast<const float4*>(x)[r2.x & 0x1FFFF];

    if (f0 < cnt) {
        int dl = r0.x >> 17; float w = __uint_as_float(r0.y);
        atomicAdd(&accf[dl * 4 + 0], xv0.x * w);
        atomicAdd(&accf[dl * 4 + 1], xv0.y * w);
        atomicAdd(&accf[dl * 4 + 2], xv0.z * w);
        atomicAdd(&accf[dl * 4 + 3], xv0.w * w);
    }
    if (f1 < cnt) {
        int dl = r1.x >> 17; float w = __uint_as_float(r1.y);
        atomicAdd(&accf[dl * 4 + 0], xv1.x * w);
        atomicAdd(&accf[dl * 4 + 1], xv1.y * w);
        atomicAdd(&accf[dl * 4 + 2], xv1.z * w);
        atomicAdd(&accf[dl * 4 + 3], xv1.w * w);
    }
    if (f2 < cnt) {
        int dl = r2.x >> 17; float w = __uint_as_float(r2.y);
        atomicAdd(&accf[dl * 4 + 0], xv2.x * w);
        atomicAdd(&accf[dl * 4 + 1], xv2.y * w);
        atomicAdd(&accf[dl * 4 + 2], xv2.z * w);
        atomicAdd(&accf[dl * 4 + 3], xv2.w * w);
    }
    // Tail (statistically never: cnt > 1536 is >7 sigma above the 1280 mean).
    for (int f = tid + 3 * CT; f < cnt; f += CT) {
        int rn = (f < RUNOF_CAP) ? (int)run_of[f] : find_run(pfx, f);
        uint2 rec = recs[(size_t)rbase[rn] + (f - pfx[rn])];
        int src = rec.x & 0x1FFFF;
        int dl  = rec.x >> 17;
        float w = __uint_as_float(rec.y);
        float4 xv = reinterpret_cast<const float4*>(x)[src];
        atomicAdd(&accf[dl * 4 + 0], xv.x * w);
        atomicAdd(&accf[dl * 4 + 1], xv.y * w);
        atomicAdd(&accf[dl * 4 + 2], xv.z * w);
        atomicAdd(&accf[dl * 4 + 3], xv.w * w);
    }
    __syncthreads();

    if (tid >= NB) return;
    const int n = b * NB + tid;

    float4 xv = reinterpret_cast<const float4*>(x)[n];
    float4 av = make_float4(accf[tid * 4 + 0], accf[tid * 4 + 1],
                            accf[tid * 4 + 2], accf[tid * 4 + 3]);

    const float4* pw = reinterpret_cast<const float4*>(packed);
    float srel = 0.f, sroot = 0.f;
#pragma unroll 4
    for (int j = 0; j < HIDDEN; ++j) {
        float4 wr = pw[j * 3 + 0];   // W1_rel[0..3][j]
        float4 wo = pw[j * 3 + 1];   // W1_root[0..3][j]
        float4 wb = pw[j * 3 + 2];   // b1, W2_rel, W2_root, pad
        float pre = wb.x
                  + av.x * wr.x + av.y * wr.y + av.z * wr.z + av.w * wr.w
                  + xv.x * wo.x + xv.y * wo.y + xv.z * wo.z + xv.w * wo.w;
        float h = fmaxf(pre, 0.f);
        srel  += h * wb.y;
        sroot += h * wb.z;
    }
    s_rel[n] = srel;
    out[n]   = sroot + b2[0];
}

// ---------------------------------------------------------------------------
// Layer-2 scalar aggregation for bucket b; non-atomic out +=.
// ---------------------------------------------------------------------------
__global__ __launch_bounds__(CT) void agg2_kernel(
    const uint2* __restrict__ recs, const int* __restrict__ bs,
    const float* __restrict__ s_rel, float* __restrict__ out) {
    __shared__ float acc[NB];
    __shared__ int   rbase[PB];
    __shared__ int   pfx[PB + 1];
    __shared__ short run_of[RUNOF_CAP];

    const int tid = threadIdx.x;
    const int b   = blockIdx.x;

    for (int i = tid; i < NB; i += CT) acc[i] = 0.f;
    const int cnt = build_runs(bs, b, rbase, pfx, run_of);

    const int f0 = tid, f1 = tid + CT, f2 = tid + 2 * CT;
    uint2 r0, r1, r2;
    if (f0 < cnt) { int rn = run_of[f0]; r0 = recs[(size_t)rbase[rn] + (f0 - pfx[rn])]; }
    if (f1 < cnt) { int rn = run_of[f1]; r1 = recs[(size_t)rbase[rn] + (f1 - pfx[rn])]; }
    if (f2 < cnt) { int rn = run_of[f2]; r2 = recs[(size_t)rbase[rn] + (f2 - pfx[rn])]; }

    float s0 = 0.f, s1 = 0.f, s2 = 0.f;
    if (f0 < cnt) s0 = s_rel[r0.x & 0x1FFFF];
    if (f1 < cnt) s1 = s_rel[r1.x & 0x1FFFF];
    if (f2 < cnt) s2 = s_rel[r2.x & 0x1FFFF];

    if (f0 < cnt) atomicAdd(&acc[r0.x >> 17], s0 * __uint_as_float(r0.y));
    if (f1 < cnt) atomicAdd(&acc[r1.x >> 17], s1 * __uint_as_float(r1.y));
    if (f2 < cnt) atomicAdd(&acc[r2.x >> 17], s2 * __uint_as_float(r2.y));

    for (int f = tid + 3 * CT; f < cnt; f += CT) {
        int rn = (f < RUNOF_CAP) ? (int)run_of[f] : find_run(pfx, f);
        uint2 rec = recs[(size_t)rbase[rn] + (f - pfx[rn])];
        atomicAdd(&acc[rec.x >> 17], s_rel[rec.x & 0x1FFFF] * __uint_as_float(rec.y));
    }
    __syncthreads();

    if (tid < NB)
        out[b * NB + tid] += acc[tid];
}

// ---------------------------------------------------------------------------
// Legacy fallback (ws too small): direct global-atomic path.
// ---------------------------------------------------------------------------
__global__ void prep_legacy(const float* __restrict__ W1_rel,
                            const float* __restrict__ b1,
                            const float* __restrict__ W1_root,
                            const float* __restrict__ W2_rel,
                            const float* __restrict__ W2_root,
                            float* __restrict__ packed) {
    int t = threadIdx.x;
    if (t < HIDDEN) {
        float* p = packed + t * 12;
#pragma unroll
        for (int k = 0; k < 4; ++k) p[k]     = W1_rel[k * HIDDEN + t];
#pragma unroll
        for (int k = 0; k < 4; ++k) p[4 + k] = W1_root[k * HIDDEN + t];
        p[8]  = b1[t];
        p[9]  = W2_rel[t];
        p[10] = W2_root[t];
        p[11] = 0.f;
    }
}

__global__ void scatter1_legacy(const int* __restrict__ ei, const float* __restrict__ ea,
                                const float* __restrict__ x, float* __restrict__ agg) {
    int e = blockIdx.x * blockDim.x + threadIdx.x;
    if (e >= N_EDGES) return;
    int src = ei[e], dst = ei[N_EDGES + e];
    float w = ea[e];
    float4 xv = reinterpret_cast<const float4*>(x)[src];
    atomicAdd(&agg[dst * 4 + 0], xv.x * w);
    atomicAdd(&agg[dst * 4 + 1], xv.y * w);
    atomicAdd(&agg[dst * 4 + 2], xv.z * w);
    atomicAdd(&agg[dst * 4 + 3], xv.w * w);
}

__global__ __launch_bounds__(256) void node_legacy(const float* __restrict__ x,
                            const float* __restrict__ agg,
                            const float* __restrict__ packed,
                            const float* __restrict__ b2,
                            float* __restrict__ s_rel,
                            float* __restrict__ out) {
    int n = blockIdx.x * blockDim.x + threadIdx.x;
    if (n >= N_NODES) return;
    float4 xv = reinterpret_cast<const float4*>(x)[n];
    float4 av = reinterpret_cast<const float4*>(agg)[n];
    const float4* pw = reinterpret_cast<const float4*>(packed);
    float srel = 0.f, sroot = 0.f;
#pragma unroll 4
    for (int j = 0; j < HIDDEN; ++j) {
        float4 wr = pw[j * 3 + 0];
        float4 wo = pw[j * 3 + 1];
        float4 wb = pw[j * 3 + 2];
        float pre = wb.x
                  + av.x * wr.x + av.y * wr.y + av.z * wr.z + av.w * wr.w
                  + xv.x * wo.x + xv.y * wo.y + xv.z * wo.z + xv.w * wo.w;
        float h = fmaxf(pre, 0.f);
        srel  += h * wb.y;
        sroot += h * wb.z;
    }
    s_rel[n] = srel;
    out[n]   = sroot + b2[0];
}

__global__ void scatter2_legacy(const int* __restrict__ ei, const float* __restrict__ ea,
                                const float* __restrict__ s_rel, float* __restrict__ out) {
    int e = blockIdx.x * blockDim.x + threadIdx.x;
    if (e >= N_EDGES) return;
    atomicAdd(&out[ei[N_EDGES + e]], s_rel[ei[e]] * ea[e]);
}

extern "C" void kernel_launch(void* const* d_in, const int* in_sizes, int n_in,
                              void* d_out, int out_size, void* d_ws, size_t ws_size,
                              hipStream_t stream) {
    const float* x       = (const float*)d_in[0];
    const int*   ei      = (const int*)  d_in[1];
    const float* ea      = (const float*)d_in[2];
    const float* W1_rel  = (const float*)d_in[3];
    const float* b1      = (const float*)d_in[4];
    const float* W1_root = (const float*)d_in[5];
    const float* W2_rel  = (const float*)d_in[6];
    const float* b2      = (const float*)d_in[7];
    const float* W2_root = (const float*)d_in[8];
    float* out = (float*)d_out;
    char*  ws  = (char*)d_ws;

    // ws layout: packed [1536 f] | s_rel [N f] | bs [(NBKT+1)*PB i] | recs [E u2]
    float* packed = (float*)ws;
    float* s_rel  = packed + 1536;
    int*   bs     = (int*)(s_rel + N_NODES);
    uint2* recs   = (uint2*)(bs + (NBKT + 1) * PB);
    const size_t need = 1536 * 4 + (size_t)N_NODES * 4 +
                        (size_t)(NBKT + 1) * PB * 4 + (size_t)N_EDGES * 8;

    if (ws_size >= need) {
        partition_kernel<<<PB, PT, 0, stream>>>(ei, ea, W1_rel, b1, W1_root,
                                                W2_rel, W2_root, recs, bs, packed);
        fused_kernel<<<NBKT, CT, 0, stream>>>(recs, bs, x, packed, b2, s_rel, out);
        agg2_kernel<<<NBKT, CT, 0, stream>>>(recs, bs, s_rel, out);
    } else {
        // Legacy global-atomic path; agg array lives where recs would.
        float* agg = (float*)recs;
        dim3 grdE((N_EDGES + 255) / 256);
        dim3 grdN((N_NODES + 255) / 256);
        prep_legacy<<<1, 256, 0, stream>>>(W1_rel, b1, W1_root, W2_rel, W2_root, packed);
        hipMemsetAsync(agg, 0, (size_t)N_NODES * 4 * sizeof(float), stream);
        scatter1_legacy<<<grdE, 256, 0, stream>>>(ei, ea, x, agg);
        node_legacy<<<grdN, 256, 0, stream>>>(x, agg, packed, b2, s_rel, out);
        scatter2_legacy<<<grdE, 256, 0, stream>>>(ei, ea, s_rel, out);
    }
}

// Round 10
// 45.854 us; speedup vs baseline: 5.6206x; 1.1614x over previous
//
#include <hip/hip_runtime.h>

#define N_NODES 100000
#define N_EDGES 640000
#define HIDDEN  128

#define NB    200              // nodes per bucket
#define NBKT  500              // buckets; NB*NBKT == N_NODES
#define PB    250              // partition blocks
#define PT    512              // partition threads (8 waves/block)
#define EPT   5                // edges/thread: PB*PT*EPT == N_EDGES
#define BLK_RECS (PT * EPT)    // 2560 records per partition block
#define CT    512              // consumer threads
#define RUNOF_CAP 2560         // run_of table entries (>> any realistic cnt)
#define CAP2  2048             // compacted per-bucket record capacity (21 sigma)
#define BSROW (NBKT + 1)       // bs_t row stride (incl. sentinel)

// ---------------------------------------------------------------------------
// Partition (+weight prep in block 0).
// Each block LDS-sorts its 2560 edge records by dst bucket, then:
//   - streams them to its OWN region recs[pb*2560..] (fully coalesced)
//   - writes its 501-entry offset row bs_t[pb][.] CONTIGUOUSLY (coalesced;
//     the old layout was 125K scattered 4B writes = message-rate wall).
// Record: x = src | (dst_local << 17), y = w bits.
// ---------------------------------------------------------------------------
__global__ __launch_bounds__(PT) void partition_kernel(
    const int* __restrict__ ei, const float* __restrict__ ea,
    const float* __restrict__ W1_rel, const float* __restrict__ b1,
    const float* __restrict__ W1_root, const float* __restrict__ W2_rel,
    const float* __restrict__ W2_root,
    uint2* __restrict__ recs, int* __restrict__ bs_t,
    float* __restrict__ packed) {
    const int tid = threadIdx.x;
    const int pb  = blockIdx.x;

    if (pb == 0 && tid < HIDDEN) {
        float* p = packed + tid * 12;
#pragma unroll
        for (int k = 0; k < 4; ++k) p[k]     = W1_rel[k * HIDDEN + tid];
#pragma unroll
        for (int k = 0; k < 4; ++k) p[4 + k] = W1_root[k * HIDDEN + tid];
        p[8]  = b1[tid];
        p[9]  = W2_rel[tid];
        p[10] = W2_root[tid];
        p[11] = 0.f;
    }

    __shared__ int   hist[NBKT];
    __shared__ int   start[NBKT];
    __shared__ int   wcur[NBKT];
    __shared__ uint2 srec[BLK_RECS];   // 20 KB

    for (int i = tid; i < NBKT; i += PT) hist[i] = 0;
    __syncthreads();

    int   dsts[EPT];
    int   srcs[EPT];
    float wts[EPT];
    const int e0 = pb * BLK_RECS + tid;
#pragma unroll
    for (int k = 0; k < EPT; ++k) {
        int e = e0 + k * PT;
        srcs[k] = ei[e];
        dsts[k] = ei[N_EDGES + e];
        wts[k]  = ea[e];
        atomicAdd(&hist[dsts[k] / NB], 1);
    }
    __syncthreads();

    // Single-wave exclusive scan of hist -> start/wcur.
    if (tid < 64) {
        int base = 0;
        for (int c = 0; c < NBKT; c += 64) {
            int idx = c + tid;
            int v = (idx < NBKT) ? hist[idx] : 0;
            int orig = v;
#pragma unroll
            for (int off = 1; off < 64; off <<= 1) {
                int t = __shfl_up(v, off);
                if (tid >= off) v += t;
            }
            if (idx < NBKT) {
                start[idx] = base + v - orig;
                wcur[idx]  = base + v - orig;
            }
            base += __shfl(v, 63);
        }
    }
    __syncthreads();

    // Publish offset row contiguously (coalesced streaming write).
    for (int i = tid; i < NBKT; i += PT) bs_t[pb * BSROW + i] = start[i];
    if (tid == 0) bs_t[pb * BSROW + NBKT] = BLK_RECS;

    // Scatter records into LDS in bucket-sorted order.
#pragma unroll
    for (int k = 0; k < EPT; ++k) {
        int d  = dsts[k];
        int b  = d / NB;
        int dl = d - b * NB;
        int slot = atomicAdd(&wcur[b], 1);
        srec[slot] = make_uint2((unsigned)srcs[k] | ((unsigned)dl << 17),
                                __float_as_uint(wts[k]));
    }
    __syncthreads();

    // Stream the sorted block to global — fully coalesced.
    uint2* dst = recs + (size_t)pb * BLK_RECS;
    for (int j = tid; j < BLK_RECS; j += PT) dst[j] = srec[j];
}

// ---------------------------------------------------------------------------
// find_run: rare-path binary search (cnt > RUNOF_CAP only).
// ---------------------------------------------------------------------------
__device__ __forceinline__ int find_run(const int* pfx, int f) {
    int lo = 0, hi = PB;
    while (hi - lo > 1) {
        int m = (lo + hi) >> 1;
        if (pfx[m] <= f) lo = m; else hi = m;
    }
    return lo;
}

// ---------------------------------------------------------------------------
// FUSED layer-1 aggregation + per-node MLP for bucket b = blockIdx.x.
// Also COMPACTS the bucket's records to crecs[b*CAP2..] (coalesced write) and
// publishes cnts[b], so agg2 needs no run-walk at all.
// ---------------------------------------------------------------------------
__global__ __launch_bounds__(CT) void fused_kernel(
    const uint2* __restrict__ recs, const int* __restrict__ bs_t,
    const float* __restrict__ x, const float* __restrict__ packed,
    const float* __restrict__ b2, float* __restrict__ s_rel,
    float* __restrict__ out, uint2* __restrict__ crecs,
    int* __restrict__ cnts) {
    __shared__ float accf[NB * 4];
    __shared__ int   rbase[PB];
    __shared__ int   lenA[PB];
    __shared__ int   pfx[PB + 1];
    __shared__ short run_of[RUNOF_CAP];

    const int tid = threadIdx.x;
    const int b   = blockIdx.x;

    for (int i = tid; i < NB * 4; i += CT) accf[i] = 0.f;

    // Build run index (strided reads of the transposed bs).
    if (tid < PB) {
        const int* row = bs_t + tid * BSROW;
        int s = row[b];
        int e = row[b + 1];
        rbase[tid] = tid * BLK_RECS + s;
        lenA[tid]  = e - s;
    }
    __syncthreads();
    if (tid < 64) {
        int base = 0;
        for (int c = 0; c < PB; c += 64) {
            int idx = c + tid;
            int v = (idx < PB) ? lenA[idx] : 0;
            int orig = v;
#pragma unroll
            for (int off = 1; off < 64; off <<= 1) {
                int t = __shfl_up(v, off);
                if (tid >= off) v += t;
            }
            if (idx < PB) pfx[idx] = base + v - orig;
            base += __shfl(v, 63);
        }
        if (tid == 0) pfx[PB] = base;
    }
    __syncthreads();
    const int cnt = pfx[PB];
    if (tid == 0) cnts[b] = cnt;
    if (tid < PB) {
        int s = pfx[tid];
        int e = pfx[tid + 1];
        if (e > RUNOF_CAP) e = RUNOF_CAP;
        for (int j = s; j < e; ++j) run_of[j] = (short)tid;
    }
    __syncthreads();

    // Gather records, accumulate layer-1 messages, compact to crecs.
    for (int f = tid; f < cnt; f += CT) {
        int rn = (f < RUNOF_CAP) ? (int)run_of[f] : find_run(pfx, f);
        uint2 rec = recs[(size_t)rbase[rn] + (f - pfx[rn])];
        if (f < CAP2) crecs[(size_t)b * CAP2 + f] = rec;
        int src = rec.x & 0x1FFFF;
        int dl  = rec.x >> 17;
        float w = __uint_as_float(rec.y);
        float4 xv = reinterpret_cast<const float4*>(x)[src];
        atomicAdd(&accf[dl * 4 + 0], xv.x * w);
        atomicAdd(&accf[dl * 4 + 1], xv.y * w);
        atomicAdd(&accf[dl * 4 + 2], xv.z * w);
        atomicAdd(&accf[dl * 4 + 3], xv.w * w);
    }
    __syncthreads();

    if (tid >= NB) return;
    const int n = b * NB + tid;

    float4 xv = reinterpret_cast<const float4*>(x)[n];
    float4 av = make_float4(accf[tid * 4 + 0], accf[tid * 4 + 1],
                            accf[tid * 4 + 2], accf[tid * 4 + 3]);

    const float4* pw = reinterpret_cast<const float4*>(packed);
    float srel = 0.f, sroot = 0.f;
#pragma unroll 4
    for (int j = 0; j < HIDDEN; ++j) {
        float4 wr = pw[j * 3 + 0];   // W1_rel[0..3][j]
        float4 wo = pw[j * 3 + 1];   // W1_root[0..3][j]
        float4 wb = pw[j * 3 + 2];   // b1, W2_rel, W2_root, pad
        float pre = wb.x
                  + av.x * wr.x + av.y * wr.y + av.z * wr.z + av.w * wr.w
                  + xv.x * wo.x + xv.y * wo.y + xv.z * wo.z + xv.w * wo.w;
        float h = fmaxf(pre, 0.f);
        srel  += h * wb.y;
        sroot += h * wb.z;
    }
    s_rel[n] = srel;
    out[n]   = sroot + b2[0];
}

// ---------------------------------------------------------------------------
// Layer-2 scalar aggregation for bucket b: contiguous crecs stream (fast
// path) or run-walk fallback (cnt > CAP2, statistically never).
// ---------------------------------------------------------------------------
__global__ __launch_bounds__(CT) void agg2_kernel(
    const uint2* __restrict__ recs, const int* __restrict__ bs_t,
    const uint2* __restrict__ crecs, const int* __restrict__ cnts,
    const float* __restrict__ s_rel, float* __restrict__ out) {
    __shared__ float acc[NB];

    const int tid = threadIdx.x;
    const int b   = blockIdx.x;

    for (int i = tid; i < NB; i += CT) acc[i] = 0.f;
    const int cnt = cnts[b];
    __syncthreads();

    if (cnt <= CAP2) {
        const uint2* r = crecs + (size_t)b * CAP2;
        for (int f = tid; f < cnt; f += CT) {
            uint2 rec = r[f];
            atomicAdd(&acc[rec.x >> 17],
                      s_rel[rec.x & 0x1FFFF] * __uint_as_float(rec.y));
        }
    } else {
        // Rare fallback: rebuild runs and walk them.
        __shared__ int rbase[PB];
        __shared__ int lenA[PB];
        __shared__ int pfx[PB + 1];
        if (tid < PB) {
            const int* row = bs_t + tid * BSROW;
            int s = row[b];
            int e = row[b + 1];
            rbase[tid] = tid * BLK_RECS + s;
            lenA[tid]  = e - s;
        }
        __syncthreads();
        if (tid < 64) {
            int base = 0;
            for (int c = 0; c < PB; c += 64) {
                int idx = c + tid;
                int v = (idx < PB) ? lenA[idx] : 0;
                int orig = v;
#pragma unroll
                for (int off = 1; off < 64; off <<= 1) {
                    int t = __shfl_up(v, off);
                    if (tid >= off) v += t;
                }
                if (idx < PB) pfx[idx] = base + v - orig;
                base += __shfl(v, 63);
            }
            if (tid == 0) pfx[PB] = base;
        }
        __syncthreads();
        for (int f = tid; f < cnt; f += CT) {
            int rn = find_run(pfx, f);
            uint2 rec = recs[(size_t)rbase[rn] + (f - pfx[rn])];
            atomicAdd(&acc[rec.x >> 17],
                      s_rel[rec.x & 0x1FFFF] * __uint_as_float(rec.y));
        }
    }
    __syncthreads();

    if (tid < NB)
        out[b * NB + tid] += acc[tid];
}

// ---------------------------------------------------------------------------
// Legacy fallback (ws too small): direct global-atomic path.
// ---------------------------------------------------------------------------
__global__ void prep_legacy(const float* __restrict__ W1_rel,
                            const float* __restrict__ b1,
                            const float* __restrict__ W1_root,
                            const float* __restrict__ W2_rel,
                            const float* __restrict__ W2_root,
                            float* __restrict__ packed) {
    int t = threadIdx.x;
    if (t < HIDDEN) {
        float* p = packed + t * 12;
#pragma unroll
        for (int k = 0; k < 4; ++k) p[k]     = W1_rel[k * HIDDEN + t];
#pragma unroll
        for (int k = 0; k < 4; ++k) p[4 + k] = W1_root[k * HIDDEN + t];
        p[8]  = b1[t];
        p[9]  = W2_rel[t];
        p[10] = W2_root[t];
        p[11] = 0.f;
    }
}

__global__ void scatter1_legacy(const int* __restrict__ ei, const float* __restrict__ ea,
                                const float* __restrict__ x, float* __restrict__ agg) {
    int e = blockIdx.x * blockDim.x + threadIdx.x;
    if (e >= N_EDGES) return;
    int src = ei[e], dst = ei[N_EDGES + e];
    float w = ea[e];
    float4 xv = reinterpret_cast<const float4*>(x)[src];
    atomicAdd(&agg[dst * 4 + 0], xv.x * w);
    atomicAdd(&agg[dst * 4 + 1], xv.y * w);
    atomicAdd(&agg[dst * 4 + 2], xv.z * w);
    atomicAdd(&agg[dst * 4 + 3], xv.w * w);
}

__global__ __launch_bounds__(256) void node_legacy(const float* __restrict__ x,
                            const float* __restrict__ agg,
                            const float* __restrict__ packed,
                            const float* __restrict__ b2,
                            float* __restrict__ s_rel,
                            float* __restrict__ out) {
    int n = blockIdx.x * blockDim.x + threadIdx.x;
    if (n >= N_NODES) return;
    float4 xv = reinterpret_cast<const float4*>(x)[n];
    float4 av = reinterpret_cast<const float4*>(agg)[n];
    const float4* pw = reinterpret_cast<const float4*>(packed);
    float srel = 0.f, sroot = 0.f;
#pragma unroll 4
    for (int j = 0; j < HIDDEN; ++j) {
        float4 wr = pw[j * 3 + 0];
        float4 wo = pw[j * 3 + 1];
        float4 wb = pw[j * 3 + 2];
        float pre = wb.x
                  + av.x * wr.x + av.y * wr.y + av.z * wr.z + av.w * wr.w
                  + xv.x * wo.x + xv.y * wo.y + xv.z * wo.z + xv.w * wo.w;
        float h = fmaxf(pre, 0.f);
        srel  += h * wb.y;
        sroot += h * wb.z;
    }
    s_rel[n] = srel;
    out[n]   = sroot + b2[0];
}

__global__ void scatter2_legacy(const int* __restrict__ ei, const float* __restrict__ ea,
                                const float* __restrict__ s_rel, float* __restrict__ out) {
    int e = blockIdx.x * blockDim.x + threadIdx.x;
    if (e >= N_EDGES) return;
    atomicAdd(&out[ei[N_EDGES + e]], s_rel[ei[e]] * ea[e]);
}

extern "C" void kernel_launch(void* const* d_in, const int* in_sizes, int n_in,
                              void* d_out, int out_size, void* d_ws, size_t ws_size,
                              hipStream_t stream) {
    const float* x       = (const float*)d_in[0];
    const int*   ei      = (const int*)  d_in[1];
    const float* ea      = (const float*)d_in[2];
    const float* W1_rel  = (const float*)d_in[3];
    const float* b1      = (const float*)d_in[4];
    const float* W1_root = (const float*)d_in[5];
    const float* W2_rel  = (const float*)d_in[6];
    const float* b2      = (const float*)d_in[7];
    const float* W2_root = (const float*)d_in[8];
    float* out = (float*)d_out;
    char*  ws  = (char*)d_ws;

    // ws layout: packed [1536 f] | s_rel [N f] | cnts [NBKT i] |
    //            bs_t [PB*BSROW i] | recs [E u2] | crecs [NBKT*CAP2 u2]
    float* packed = (float*)ws;
    float* s_rel  = packed + 1536;
    int*   cnts   = (int*)(s_rel + N_NODES);
    int*   bs_t   = cnts + NBKT;
    uint2* recs   = (uint2*)(bs_t + PB * BSROW);
    uint2* crecs  = recs + (size_t)N_EDGES;
    const size_t need = 1536 * 4 + (size_t)N_NODES * 4 + NBKT * 4 +
                        (size_t)PB * BSROW * 4 + (size_t)N_EDGES * 8 +
                        (size_t)NBKT * CAP2 * 8;

    if (ws_size >= need) {
        partition_kernel<<<PB, PT, 0, stream>>>(ei, ea, W1_rel, b1, W1_root,
                                                W2_rel, W2_root, recs, bs_t, packed);
        fused_kernel<<<NBKT, CT, 0, stream>>>(recs, bs_t, x, packed, b2,
                                              s_rel, out, crecs, cnts);
        agg2_kernel<<<NBKT, CT, 0, stream>>>(recs, bs_t, crecs, cnts, s_rel, out);
    } else {
        // Legacy global-atomic path; agg array lives where recs would.
        float* agg = (float*)recs;
        dim3 grdE((N_EDGES + 255) / 256);
        dim3 grdN((N_NODES + 255) / 256);
        prep_legacy<<<1, 256, 0, stream>>>(W1_rel, b1, W1_root, W2_rel, W2_root, packed);
        hipMemsetAsync(agg, 0, (size_t)N_NODES * 4 * sizeof(float), stream);
        scatter1_legacy<<<grdE, 256, 0, stream>>>(ei, ea, x, agg);
        node_legacy<<<grdN, 256, 0, stream>>>(x, agg, packed, b2, s_rel, out);
        scatter2_legacy<<<grdE, 256, 0, stream>>>(ei, ea, s_rel, out);
    }
}